// Round 5
// baseline (423.969 us; speedup 1.0000x reference)
//
#include <hip/hip_runtime.h>

constexpr int NN = 50000;   // nodes
constexpr int MP = 50048;   // padded to 391*128
constexpr int NE = 800000;  // edges
constexpr int KV = 300;     // vocab / in_dim
constexpr int KP1 = 320;    // padded K for layer 1 (5 x BK64)
constexpr int DE = 256;     // embed
constexpr int DF = 128;     // fc dim
constexpr int NC = 4;       // classes

typedef __attribute__((ext_vector_type(8))) short bf16x8;
typedef __attribute__((ext_vector_type(4))) float f32x4;

__device__ inline float b2f(ushort u) { return __uint_as_float((uint)u << 16); }
__device__ inline ushort f2b(float f) {
    uint u = __float_as_uint(f);
    u += 0x7fffu + ((u >> 16) & 1u);   // RNE (finite inputs only)
    return (ushort)(u >> 16);
}
__device__ inline void gload_lds16(const void* g, void* l) {
    __builtin_amdgcn_global_load_lds(
        (const __attribute__((address_space(1))) void*)g,
        (__attribute__((address_space(3))) void*)l, 16, 0, 0);
}

// ------------------------------------------------------------------ scans
__global__ __launch_bounds__(256) void k_scan1(const int* __restrict__ deg,
                                               int* __restrict__ partial) {
    __shared__ int sd[256];
    int t = threadIdx.x;
    int n = blockIdx.x * 256 + t;
    sd[t] = (n < NN) ? deg[n] : 0;
    __syncthreads();
    for (int off = 128; off > 0; off >>= 1) {
        if (t < off) sd[t] += sd[t + off];
        __syncthreads();
    }
    if (t == 0) partial[blockIdx.x] = sd[0];
}

__global__ __launch_bounds__(256) void k_scan2(const int* __restrict__ partial,
                                               int* __restrict__ poff, int nb) {
    __shared__ int sd[256];
    int t = threadIdx.x;
    int v = (t < nb) ? partial[t] : 0;
    sd[t] = v;
    __syncthreads();
    for (int off = 1; off < 256; off <<= 1) {
        int x = (t >= off) ? sd[t - off] : 0;
        __syncthreads();
        sd[t] += x;
        __syncthreads();
    }
    poff[t] = sd[t] - v;
}

__global__ __launch_bounds__(256) void k_scan3(const int* __restrict__ deg,
                                               const int* __restrict__ poff,
                                               int* __restrict__ rowptr) {
    __shared__ int sd[256];
    int t = threadIdx.x;
    int n = blockIdx.x * 256 + t;
    int v = (n < NN) ? deg[n] : 0;
    sd[t] = v;
    __syncthreads();
    for (int off = 1; off < 256; off <<= 1) {
        int x = (t >= off) ? sd[t - off] : 0;
        __syncthreads();
        sd[t] += x;
        __syncthreads();
    }
    if (n < NN) rowptr[n] = poff[blockIdx.x] + sd[t] - v;
    if (blockIdx.x == 0 && t == 0) rowptr[NN] = NE;
}

// ------------------------------------------------------- conversion bodies
__device__ inline void cvt8_store(const float* s, int valid, ushort* dptr) {
    float f[8] = {0.f, 0.f, 0.f, 0.f, 0.f, 0.f, 0.f, 0.f};
    if (valid >= 8) {
        float4 v0 = *(const float4*)s;
        float4 v1 = *(const float4*)(s + 4);
        f[0] = v0.x; f[1] = v0.y; f[2] = v0.z; f[3] = v0.w;
        f[4] = v1.x; f[5] = v1.y; f[6] = v1.z; f[7] = v1.w;
    } else {
#pragma unroll
        for (int j = 0; j < 8; ++j)
            if (j < valid) f[j] = s[j];
    }
    ushort v[8];
#pragma unroll
    for (int j = 0; j < 8; ++j) v[j] = f2b(f[j]);
    uint4 pk;
    pk.x = (uint)v[0] | ((uint)v[1] << 16);
    pk.y = (uint)v[2] | ((uint)v[3] << 16);
    pk.z = (uint)v[4] | ((uint)v[5] << 16);
    pk.w = (uint)v[6] | ((uint)v[7] << 16);
    *(uint4*)dptr = pk;
}

__device__ inline void cvt_x_body(int blk, const float* __restrict__ x,
                                  ushort* __restrict__ xb) {
    int i = blk * 256 + threadIdx.x;
    if (i >= MP * (KP1 / 8)) return;
    int row = i / (KP1 / 8);
    int kb = (i % (KP1 / 8)) * 8;
    if (row < NN) {
        cvt8_store(x + (size_t)row * KV + kb, KV - kb, xb + (size_t)row * KP1 + kb);
    } else {
        uint4 z = {0u, 0u, 0u, 0u};
        *(uint4*)(xb + (size_t)row * KP1 + kb) = z;
    }
}

__device__ inline void cvt_wall_body(int blk,
                                     const float* __restrict__ w1l,
                                     const float* __restrict__ w1r,
                                     const float* __restrict__ w2l,
                                     const float* __restrict__ w2r,
                                     const float* __restrict__ cw1,
                                     ushort* __restrict__ wcat1,
                                     ushort* __restrict__ wcat2,
                                     ushort* __restrict__ cw1b) {
    int i = blk * 256 + threadIdx.x;
    const float* src; ushort* dst; int row, kb, Kin;
    if (i < 10240)      { int g = i;         row = g / 40; kb = (g % 40) * 8; src = w1l; dst = wcat1;                     Kin = KV; }
    else if (i < 20480) { int g = i - 10240; row = g / 40; kb = (g % 40) * 8; src = w1r; dst = wcat1 + (size_t)256 * KP1; Kin = KV; }
    else if (i < 28672) { int g = i - 20480; row = g / 32; kb = (g % 32) * 8; src = w2l; dst = wcat2;                     Kin = DE; }
    else if (i < 36864) { int g = i - 28672; row = g / 32; kb = (g % 32) * 8; src = w2r; dst = wcat2 + (size_t)256 * DE;  Kin = DE; }
    else if (i < 40960) { int g = i - 36864; row = g / 32; kb = (g % 32) * 8; src = cw1; dst = cw1b;                      Kin = DE; }
    else return;
    int KPr = (Kin == KV) ? KP1 : DE;
    cvt8_store(src + (size_t)row * Kin + kb, Kin - kb, dst + (size_t)row * KPr + kb);
}

// ---------------------------------------- fused prep: degree | cvt_x | cvt_w
// grid 7*1610 = 11270: r<2 -> degree (s=2q+r), r>=2 -> w=5q+(r-2):
// w<7820 cvt_x, 7820<=w<7980 cvt_wall.
__global__ __launch_bounds__(256) void k_prep(const float* __restrict__ x,
                                              const int* __restrict__ dst,
                                              const float* __restrict__ w1l,
                                              const float* __restrict__ w1r,
                                              const float* __restrict__ w2l,
                                              const float* __restrict__ w2r,
                                              const float* __restrict__ cw1,
                                              ushort* __restrict__ xb,
                                              ushort* __restrict__ wcat1,
                                              ushort* __restrict__ wcat2,
                                              ushort* __restrict__ cw1b,
                                              int* __restrict__ deg) {
    int bid = blockIdx.x;
    int q = bid / 7, r = bid % 7;
    if (r < 2) {
        int s = 2 * q + r;
        if (s < 3125) {
            int e = s * 256 + threadIdx.x;
            if (e < NE) atomicAdd(&deg[dst[e]], 1);
        }
    } else {
        int w = 5 * q + (r - 2);
        if (w < 7820) cvt_x_body(w, x, xb);
        else if (w < 7980)
            cvt_wall_body(w - 7820, w1l, w1r, w2l, w2r, cw1, wcat1, wcat2, cw1b);
    }
}

// -------------------------------------------------------------- layer GEMM body
__device__ inline void gemm_layer_body(const ushort* __restrict__ A,
                                       const ushort* __restrict__ B,
                                       unsigned char* __restrict__ ybuf,
                                       ushort* __restrict__ yrb,
                                       int KPr, int bn, int bm,
                                       ushort* As, ushort* Bs) {
    const int t = threadIdx.x;
    const int w = t >> 6;
    const int lane = t & 63;
    const int wr = (w >> 1) * 64, wc = (w & 1) * 64;
    const int fr = lane & 15;
    const int fg = lane >> 4;
    const int drow = (lane >> 4) * 4;
    const int dcol = lane & 15;

    f32x4 acc[4][4];
#pragma unroll
    for (int m = 0; m < 4; ++m)
#pragma unroll
        for (int n = 0; n < 4; ++n) acc[m][n] = (f32x4){0.f, 0.f, 0.f, 0.f};

    const int srow = lane >> 3;
    const int sblk = (lane & 7) ^ srow;
    const ushort* Ab = A + (size_t)(bm + w * 32 + srow) * KPr + sblk * 8;
    const ushort* Bb = B + (size_t)(bn + w * 32 + srow) * KPr + sblk * 8;
    ushort* Al = As + w * 2048 + lane * 8;
    ushort* Bl = Bs + w * 2048 + lane * 8;

    for (int k0 = 0; k0 < KPr; k0 += 64) {
#pragma unroll
        for (int j = 0; j < 4; ++j) {
            gload_lds16(Ab + k0 + (size_t)j * 8 * KPr, Al + j * 512);
            gload_lds16(Bb + k0 + (size_t)j * 8 * KPr, Bl + j * 512);
        }
        __syncthreads();
#pragma unroll
        for (int ks = 0; ks < 2; ++ks) {
            bf16x8 af[4], bfr[4];
#pragma unroll
            for (int m = 0; m < 4; ++m) {
                int row = wr + 16 * m + fr;
                int blk = (fg + 4 * ks) ^ (row & 7);
                af[m] = *(const bf16x8*)(As + row * 64 + blk * 8);
            }
#pragma unroll
            for (int n = 0; n < 4; ++n) {
                int row = wc + 16 * n + fr;
                int blk = (fg + 4 * ks) ^ (row & 7);
                bfr[n] = *(const bf16x8*)(Bs + row * 64 + blk * 8);
            }
#pragma unroll
            for (int m = 0; m < 4; ++m)
#pragma unroll
                for (int n = 0; n < 4; ++n)
                    acc[m][n] = __builtin_amdgcn_mfma_f32_16x16x32_bf16(
                        af[m], bfr[n], acc[m][n], 0, 0, 0);
        }
        __syncthreads();
    }
#pragma unroll
    for (int m = 0; m < 4; ++m) {
        int gr0 = bm + wr + 16 * m + drow;
#pragma unroll
        for (int n = 0; n < 4; ++n) {
            int gc = bn + wc + 16 * n + dcol;
#pragma unroll
            for (int r = 0; r < 4; ++r) {
                float v = acc[m][n][r];
                if (gc < 256) {
                    uint p = __builtin_amdgcn_cvt_pk_fp8_f32(v, v, 0, false);
                    ybuf[(size_t)(gr0 + r) * 256 + gc] = (unsigned char)(p & 0xff);
                } else {
                    yrb[(size_t)(gr0 + r) * 256 + (gc - 256)] = f2b(v);
                }
            }
        }
    }
}

// standalone layer GEMM (layer 2)
__global__ __launch_bounds__(256) void k_mgemm_layer(const ushort* __restrict__ A,
                                                     const ushort* __restrict__ B,
                                                     unsigned char* __restrict__ ybuf,
                                                     ushort* __restrict__ yrb,
                                                     int KPr) {
    __shared__ __align__(16) ushort As[128 * 64];
    __shared__ __align__(16) ushort Bs[128 * 64];
    gemm_layer_body(A, B, ybuf, yrb, KPr, blockIdx.x * 128, blockIdx.y * 128, As, Bs);
}

// -------------------------- fused: layer-1 GEMM | CSR scatter | mask copy
// grid 3*1564 + 196 = 4888: bid<4692: r==2 -> gemm q (bn=q&3, bm=q>>2),
// r<2 -> scatter s=2q+r (s<3125); bid>=4692 -> mask block.
__global__ __launch_bounds__(256) void k_g1s(const ushort* __restrict__ A,
                                             const ushort* __restrict__ B,
                                             unsigned char* __restrict__ ybuf,
                                             ushort* __restrict__ yrb,
                                             const int* __restrict__ src,
                                             const int* __restrict__ dst,
                                             const int* __restrict__ rowptr,
                                             int* __restrict__ cnt2,
                                             int* __restrict__ col,
                                             const unsigned char* __restrict__ m8,
                                             float* __restrict__ omask) {
    __shared__ __align__(16) ushort As[128 * 64];
    __shared__ __align__(16) ushort Bs[128 * 64];
    int bid = blockIdx.x;
    if (bid < 4692) {
        int q = bid / 3, r = bid % 3;
        if (r == 2) {
            gemm_layer_body(A, B, ybuf, yrb, KP1, (q & 3) * 128, (q >> 2) * 128,
                            As, Bs);
        } else {
            int s = 2 * q + r;
            if (s < 3125) {
                int e = s * 256 + threadIdx.x;
                if (e < NE) {
                    int d = dst[e];
                    int p = rowptr[d] + atomicAdd(&cnt2[d], 1);
                    col[p] = src[e];
                }
            }
        }
    } else {
        int i = (bid - 4692) * 256 + threadIdx.x;
        if (i < NN) {
            bool bytes = (m8[1] != 0);
            float v;
            if (bytes) v = (m8[i] != 0) ? 1.0f : 0.0f;
            else       v = (((const int*)m8)[i] != 0) ? 1.0f : 0.0f;
            omask[i] = v;
        }
    }
}

// --------------------------------------------------- aggregate + norm (+relu)
__global__ __launch_bounds__(256) void k_aggnorm(const uint* __restrict__ yl,
                                                 const ushort* __restrict__ yrb,
                                                 const float* __restrict__ bias,
                                                 const int* __restrict__ rowptr,
                                                 const int* __restrict__ col,
                                                 float* __restrict__ outf,
                                                 ushort* __restrict__ outb,
                                                 int relu) {
    int wave = threadIdx.x >> 6;
    int lane = threadIdx.x & 63;
    int n = blockIdx.x * 4 + wave;
    if (n >= NN) return;
    int beg = rowptr[n], end = rowptr[n + 1];
    const uint* base = yl + lane;
    float a0 = 0.f, a1 = 0.f, a2 = 0.f, a3 = 0.f;
    float c0 = 0.f, c1 = 0.f, c2 = 0.f, c3 = 0.f;
    int e = beg;
    for (; e + 8 <= end; e += 8) {
        uint v[8];
#pragma unroll
        for (int j = 0; j < 8; ++j) v[j] = base[(size_t)col[e + j] * 64];
#pragma unroll
        for (int j = 0; j < 8; j += 2) {
            a0 += __builtin_amdgcn_cvt_f32_fp8(v[j], 0);
            a1 += __builtin_amdgcn_cvt_f32_fp8(v[j], 1);
            a2 += __builtin_amdgcn_cvt_f32_fp8(v[j], 2);
            a3 += __builtin_amdgcn_cvt_f32_fp8(v[j], 3);
            c0 += __builtin_amdgcn_cvt_f32_fp8(v[j + 1], 0);
            c1 += __builtin_amdgcn_cvt_f32_fp8(v[j + 1], 1);
            c2 += __builtin_amdgcn_cvt_f32_fp8(v[j + 1], 2);
            c3 += __builtin_amdgcn_cvt_f32_fp8(v[j + 1], 3);
        }
    }
    for (; e < end; ++e) {
        uint v = base[(size_t)col[e] * 64];
        a0 += __builtin_amdgcn_cvt_f32_fp8(v, 0);
        a1 += __builtin_amdgcn_cvt_f32_fp8(v, 1);
        a2 += __builtin_amdgcn_cvt_f32_fp8(v, 2);
        a3 += __builtin_amdgcn_cvt_f32_fp8(v, 3);
    }
    a0 += c0; a1 += c1; a2 += c2; a3 += c3;
    int d = end - beg;
    float inv = 1.0f / (float)(d > 1 ? d : 1);
    ushort4 rv = *(const ushort4*)(yrb + (size_t)n * 256 + lane * 4);
    float4 b = *(const float4*)(bias + lane * 4);
    float hx = a0 * inv + b.x + b2f(rv.x);
    float hy = a1 * inv + b.y + b2f(rv.y);
    float hz = a2 * inv + b.z + b2f(rv.z);
    float hw = a3 * inv + b.w + b2f(rv.w);
    float ss = hx * hx + hy * hy + hz * hz + hw * hw;
#pragma unroll
    for (int off = 32; off > 0; off >>= 1) ss += __shfl_xor(ss, off, 64);
    float scale = 1.0f / fmaxf(sqrtf(ss), 1e-12f);
    hx *= scale; hy *= scale; hz *= scale; hw *= scale;
    if (relu) {
        hx = fmaxf(hx, 0.f); hy = fmaxf(hy, 0.f);
        hz = fmaxf(hz, 0.f); hw = fmaxf(hw, 0.f);
    }
    if (outf) {
        float4 o = make_float4(hx, hy, hz, hw);
        *(float4*)(outf + (size_t)n * DE + lane * 4) = o;
    }
    ushort4 ob;
    ob.x = f2b(hx); ob.y = f2b(hy); ob.z = f2b(hz); ob.w = f2b(hw);
    *(ushort4*)(outb + (size_t)n * DE + lane * 4) = ob;
}

// ----------------------------------------------- classifier GEMM + logits
__global__ __launch_bounds__(256) void k_mcls(const ushort* __restrict__ A,
                                              const ushort* __restrict__ B,
                                              const float* __restrict__ cb1,
                                              const float* __restrict__ cw2,
                                              const float* __restrict__ cb2,
                                              float* __restrict__ outp) {
    __shared__ __align__(16) ushort smem[128 * 130];
    __shared__ float cw2s[NC * DF];
    ushort* As = smem;
    ushort* Bs = smem + 8192;
    const int t = threadIdx.x;
    const int bm = blockIdx.y * 128;
    const int w = t >> 6;
    const int lane = t & 63;
    const int wr = (w >> 1) * 64, wc = (w & 1) * 64;
    const int fr = lane & 15;
    const int fg = lane >> 4;
    const int drow = (lane >> 4) * 4;
    const int dcol = lane & 15;

    for (int i = t; i < NC * DF; i += 256) cw2s[i] = cw2[i];

    f32x4 acc[4][4];
#pragma unroll
    for (int m = 0; m < 4; ++m)
#pragma unroll
        for (int n = 0; n < 4; ++n) acc[m][n] = (f32x4){0.f, 0.f, 0.f, 0.f};

    const int srow = lane >> 3;
    const int sblk = (lane & 7) ^ srow;
    const ushort* Ab = A + (size_t)(bm + w * 32 + srow) * DE + sblk * 8;
    const ushort* Bb = B + (size_t)(w * 32 + srow) * DE + sblk * 8;
    ushort* Al = As + w * 2048 + lane * 8;
    ushort* Bl = Bs + w * 2048 + lane * 8;

    for (int k0 = 0; k0 < DE; k0 += 64) {
#pragma unroll
        for (int j = 0; j < 4; ++j) {
            gload_lds16(Ab + k0 + (size_t)j * 8 * DE, Al + j * 512);
            gload_lds16(Bb + k0 + (size_t)j * 8 * DE, Bl + j * 512);
        }
        __syncthreads();
#pragma unroll
        for (int ks = 0; ks < 2; ++ks) {
            bf16x8 af[4], bfr[4];
#pragma unroll
            for (int m = 0; m < 4; ++m) {
                int row = wr + 16 * m + fr;
                int blk = (fg + 4 * ks) ^ (row & 7);
                af[m] = *(const bf16x8*)(As + row * 64 + blk * 8);
            }
#pragma unroll
            for (int n = 0; n < 4; ++n) {
                int row = wc + 16 * n + fr;
                int blk = (fg + 4 * ks) ^ (row & 7);
                bfr[n] = *(const bf16x8*)(Bs + row * 64 + blk * 8);
            }
#pragma unroll
            for (int m = 0; m < 4; ++m)
#pragma unroll
                for (int n = 0; n < 4; ++n)
                    acc[m][n] = __builtin_amdgcn_mfma_f32_16x16x32_bf16(
                        af[m], bfr[n], acc[m][n], 0, 0, 0);
        }
        __syncthreads();
    }
#pragma unroll
    for (int m = 0; m < 4; ++m) {
        int lr0 = wr + 16 * m + drow;
#pragma unroll
        for (int n = 0; n < 4; ++n) {
            int f = wc + 16 * n + dcol;
            float bv = cb1[f];
#pragma unroll
            for (int r = 0; r < 4; ++r) {
                float v = fmaxf(acc[m][n][r] + bv, 0.f);
                smem[(lr0 + r) * 130 + f] = f2b(v);
            }
        }
    }
    __syncthreads();
    int node = t >> 1;
    int half = t & 1;
    float p0 = 0.f, p1 = 0.f, p2 = 0.f, p3 = 0.f;
#pragma unroll
    for (int i = 0; i < 32; ++i) {
        uint hv = *(const uint*)&smem[node * 130 + half * 64 + 2 * i];
        float h0 = b2f((ushort)(hv & 0xffff));
        float h1 = b2f((ushort)(hv >> 16));
        int f = half * 64 + 2 * i;
        p0 += h0 * cw2s[0 * DF + f] + h1 * cw2s[0 * DF + f + 1];
        p1 += h0 * cw2s[1 * DF + f] + h1 * cw2s[1 * DF + f + 1];
        p2 += h0 * cw2s[2 * DF + f] + h1 * cw2s[2 * DF + f + 1];
        p3 += h0 * cw2s[3 * DF + f] + h1 * cw2s[3 * DF + f + 1];
    }
    p0 += __shfl_xor(p0, 1, 64);
    p1 += __shfl_xor(p1, 1, 64);
    p2 += __shfl_xor(p2, 1, 64);
    p3 += __shfl_xor(p3, 1, 64);
    int ng = bm + node;
    if (half == 0 && ng < NN) {
        float4 o = make_float4(p0 + cb2[0], p1 + cb2[1], p2 + cb2[2], p3 + cb2[3]);
        *(float4*)(outp + (size_t)ng * NC) = o;
    }
}

// ------------------------------------------------------------------- launcher
extern "C" void kernel_launch(void* const* d_in, const int* in_sizes, int n_in,
                              void* d_out, int out_size, void* d_ws, size_t ws_size,
                              hipStream_t stream) {
    const float* x   = (const float*)d_in[0];
    const int*   ei  = (const int*)d_in[1];
    const void*  msk = d_in[2];
    const float* w1l = (const float*)d_in[3];
    const float* b1l = (const float*)d_in[4];
    const float* w1r = (const float*)d_in[5];
    const float* w2l = (const float*)d_in[6];
    const float* b2l = (const float*)d_in[7];
    const float* w2r = (const float*)d_in[8];
    const float* cw1 = (const float*)d_in[9];
    const float* cb1 = (const float*)d_in[10];
    const float* cw2 = (const float*)d_in[11];
    const float* cb2 = (const float*)d_in[12];

    float* out        = (float*)d_out;
    float* out_logits = out;                              // [N,4]
    float* out_mask   = out + (size_t)NN * NC;            // [N,1]
    float* h2f        = out + (size_t)NN * NC + NN;       // [N,256]

    char* wp = (char*)d_ws;
    auto alloc = [&](size_t bytes) -> void* {
        void* p = (void*)wp;
        wp += (bytes + 255) & ~(size_t)255;
        return p;
    };
    int* counters = (int*)alloc((size_t)2 * NN * 4);
    int* deg  = counters;
    int* cnt2 = counters + NN;
    int* rowptr  = (int*)alloc((size_t)(NN + 1) * 4);
    int* partial = (int*)alloc(256 * 4);
    int* poff    = (int*)alloc(256 * 4);
    int* col     = (int*)alloc((size_t)NE * 4);
    ushort* xb    = (ushort*)alloc((size_t)MP * KP1 * 2);
    ushort* wcat1 = (ushort*)alloc((size_t)512 * KP1 * 2);
    ushort* wcat2 = (ushort*)alloc((size_t)512 * DE * 2);
    ushort* cw1b  = (ushort*)alloc((size_t)DF * DE * 2);
    unsigned char* ybuf = (unsigned char*)alloc((size_t)MP * 256);  // fp8 y_l
    ushort* yrb   = (ushort*)alloc((size_t)MP * 256 * 2);           // bf16 y_r
    ushort* h1b   = (ushort*)alloc((size_t)MP * DE * 2);
    ushort* h2b   = (ushort*)alloc((size_t)MP * DE * 2);

    const int* srcp = ei;
    const int* dstp = ei + NE;

    hipMemsetAsync(counters, 0, (size_t)2 * NN * 4, stream);
    // fused: degree || cvt_x || cvt_weights
    k_prep<<<11270, 256, 0, stream>>>(x, dstp, w1l, w1r, w2l, w2r, cw1,
                                      xb, wcat1, wcat2, cw1b, deg);
    int nb = (NN + 255) / 256;  // 196
    k_scan1<<<nb, 256, 0, stream>>>(deg, partial);
    k_scan2<<<1, 256, 0, stream>>>(partial, poff, nb);
    k_scan3<<<nb, 256, 0, stream>>>(deg, poff, rowptr);

    // fused: layer-1 GEMM || CSR scatter || mask
    k_g1s<<<4888, 256, 0, stream>>>(xb, wcat1, ybuf, yrb, srcp, dstp, rowptr,
                                    cnt2, col, (const unsigned char*)msk, out_mask);
    k_aggnorm<<<NN / 4, 256, 0, stream>>>((const uint*)ybuf, yrb, b1l, rowptr, col,
                                          nullptr, h1b, 1);
    dim3 g1(512 / 128, MP / 128);  // (4, 391)
    k_mgemm_layer<<<g1, 256, 0, stream>>>(h1b, wcat2, ybuf, yrb, DE);
    k_aggnorm<<<NN / 4, 256, 0, stream>>>((const uint*)ybuf, yrb, b2l, rowptr, col,
                                          h2f, h2b, 0);

    dim3 g2(1, MP / 128);          // (1, 391)
    k_mcls<<<g2, 256, 0, stream>>>(h2b, cw1b, cb1, cw2, cb2, out_logits);
}